// Round 2
// baseline (1428.147 us; speedup 1.0000x reference)
//
#include <hip/hip_runtime.h>

// Problem constants: B=2, N=1024 per branch, H=1024, NH=16, d=64, S=2N=2048.
// All I/O is float32 (per reference dtypes).
#define NB      2
#define NSEQ    1024
#define S2      2048
#define HDIM    1024
#define NHEADS  16
#define DHEAD   64
#define ATT_SCALE 0.125f   // d^-0.5 = 64^-0.5

// ---------------------------------------------------------------------------
// QKV GEMM: C[2048,3072] = X[2048,1024] @ W[3072,1024]^T, f32.
// Epilogue scatters to Q/K/V laid out [b, h, s, d] (f32), s = seq_off + n.
// Tile: 64x64 per block, BK=16, 256 threads, 4x4 microtile.
// ---------------------------------------------------------------------------
__global__ __launch_bounds__(256) void qkv_gemm(
    const float* __restrict__ X,
    const float* __restrict__ W,
    float* __restrict__ Q, float* __restrict__ Kd, float* __restrict__ V,
    int seq_off)
{
    __shared__ float As[16][68];   // [k][m], pad 68: float4-aligned + conflict-free
    __shared__ float Bs[16][68];   // [k][n]
    const int t    = threadIdx.x;
    const int row0 = blockIdx.y * 64;
    const int col0 = blockIdx.x * 64;
    const int tx   = t & 15, ty = t >> 4;
    const int lrow = t >> 2;          // 0..63
    const int lk4  = (t & 3) * 4;     // 0,4,8,12
    float acc[4][4] = {};

    for (int k0 = 0; k0 < HDIM; k0 += 16) {
        float4 ua = *(const float4*)(X + (size_t)(row0 + lrow) * HDIM + k0 + lk4);
        float4 ub = *(const float4*)(W + (size_t)(col0 + lrow) * HDIM + k0 + lk4);
        As[lk4 + 0][lrow] = ua.x;
        As[lk4 + 1][lrow] = ua.y;
        As[lk4 + 2][lrow] = ua.z;
        As[lk4 + 3][lrow] = ua.w;
        Bs[lk4 + 0][lrow] = ub.x;
        Bs[lk4 + 1][lrow] = ub.y;
        Bs[lk4 + 2][lrow] = ub.z;
        Bs[lk4 + 3][lrow] = ub.w;
        __syncthreads();
        #pragma unroll
        for (int kk = 0; kk < 16; ++kk) {
            float4 a4 = *(const float4*)&As[kk][ty * 4];
            float4 b4 = *(const float4*)&Bs[kk][tx * 4];
            float a[4] = {a4.x, a4.y, a4.z, a4.w};
            float b[4] = {b4.x, b4.y, b4.z, b4.w};
            #pragma unroll
            for (int i = 0; i < 4; ++i)
                #pragma unroll
                for (int j = 0; j < 4; ++j)
                    acc[i][j] += a[i] * b[j];
        }
        __syncthreads();
    }

    // col block maps to a single (qkv, head): col = qi*1024 + h*64 + dd
    const int bb = row0 >> 10;
    const int n0 = row0 & 1023;
    const int qi = col0 >> 10;
    const int h  = (col0 >> 6) & (NHEADS - 1);
    float* dstbase = (qi == 0) ? Q : ((qi == 1) ? Kd : V);
    #pragma unroll
    for (int i = 0; i < 4; ++i) {
        int n = n0 + ty * 4 + i;
        float* dst = dstbase + ((size_t)(bb * NHEADS + h) * S2 + seq_off + n) * DHEAD + tx * 4;
        float4 v = {acc[i][0], acc[i][1], acc[i][2], acc[i][3]};
        *(float4*)dst = v;
    }
}

// ---------------------------------------------------------------------------
// Attention: per (b,h) flash-style online softmax over S=2048 keys, d=64.
// Block = 32 query rows x 256 threads; thread (row=t>>3, cg=t&7) owns dims
// cg*8..cg*8+7 of its row's output accumulator.
// ---------------------------------------------------------------------------
__global__ __launch_bounds__(256) void attn_kernel(
    const float* __restrict__ Q, const float* __restrict__ K,
    const float* __restrict__ V, float* __restrict__ O)
{
    __shared__ float Qs[32][68];
    __shared__ float Ks[64][68];
    __shared__ float Vs[64][68];
    __shared__ float Ps[32][68];

    const int t  = threadIdx.x;
    const int bh = blockIdx.z * NHEADS + blockIdx.y;
    const int r0 = blockIdx.x * 32;
    const float* Qh = Q + (size_t)bh * S2 * DHEAD;
    const float* Kh = K + (size_t)bh * S2 * DHEAD;
    const float* Vh = V + (size_t)bh * S2 * DHEAD;

    {   // stage Q tile [32][64]
        int qrow = t >> 3, qcol = (t & 7) * 8;
        const float* src = Qh + (size_t)(r0 + qrow) * DHEAD + qcol;
        *(float4*)&Qs[qrow][qcol]     = *(const float4*)src;
        *(float4*)&Qs[qrow][qcol + 4] = *(const float4*)(src + 4);
    }
    __syncthreads();

    const int row = t >> 3;   // 0..31
    const int cg  = t & 7;    // 0..7

    float4 qr[16];
    #pragma unroll
    for (int d4 = 0; d4 < 16; ++d4) qr[d4] = *(const float4*)&Qs[row][d4 * 4];

    float m = -1e30f, l = 0.f;
    float acc[8] = {0.f, 0.f, 0.f, 0.f, 0.f, 0.f, 0.f, 0.f};

    const int lr = t >> 4, lc = (t & 15) * 4;   // K/V stage mapping
    for (int kt = 0; kt < S2 / 64; ++kt) {
        __syncthreads();   // previous tile's consumers done
        #pragma unroll
        for (int p = 0; p < 4; ++p) {
            int j = lr + p * 16;
            *(float4*)&Ks[j][lc] = *(const float4*)(Kh + (size_t)(kt * 64 + j) * DHEAD + lc);
            *(float4*)&Vs[j][lc] = *(const float4*)(Vh + (size_t)(kt * 64 + j) * DHEAD + lc);
        }
        __syncthreads();

        // scores: thread handles keys j = jj*8 + cg (lane-contiguous rows -> no bank conflict)
        float s[8];
        float mt = -1e30f;
        #pragma unroll
        for (int jj = 0; jj < 8; ++jj) {
            int j = jj * 8 + cg;
            float dot = 0.f;
            #pragma unroll
            for (int d4 = 0; d4 < 16; ++d4) {
                float4 k4 = *(const float4*)&Ks[j][d4 * 4];
                dot += qr[d4].x * k4.x + qr[d4].y * k4.y + qr[d4].z * k4.z + qr[d4].w * k4.w;
            }
            s[jj] = dot * ATT_SCALE;
            mt = fmaxf(mt, s[jj]);
        }
        mt = fmaxf(mt, __shfl_xor(mt, 1));
        mt = fmaxf(mt, __shfl_xor(mt, 2));
        mt = fmaxf(mt, __shfl_xor(mt, 4));
        float mnew  = fmaxf(m, mt);
        float alpha = __expf(m - mnew);
        float lsum = 0.f;
        #pragma unroll
        for (int jj = 0; jj < 8; ++jj) {
            float p = __expf(s[jj] - mnew);
            Ps[row][jj * 8 + cg] = p;
            lsum += p;
        }
        lsum += __shfl_xor(lsum, 1);
        lsum += __shfl_xor(lsum, 2);
        lsum += __shfl_xor(lsum, 4);
        l = l * alpha + lsum;
        m = mnew;
        #pragma unroll
        for (int dd = 0; dd < 8; ++dd) acc[dd] *= alpha;
        __syncthreads();   // Ps visible to whole block

        #pragma unroll 8
        for (int j = 0; j < 64; ++j) {
            float p = Ps[row][j];
            float4 v0 = *(const float4*)&Vs[j][cg * 8];
            float4 v1 = *(const float4*)&Vs[j][cg * 8 + 4];
            acc[0] += p * v0.x; acc[1] += p * v0.y; acc[2] += p * v0.z; acc[3] += p * v0.w;
            acc[4] += p * v1.x; acc[5] += p * v1.y; acc[6] += p * v1.z; acc[7] += p * v1.w;
        }
    }

    float inv = 1.f / l;
    float4 o0 = {acc[0] * inv, acc[1] * inv, acc[2] * inv, acc[3] * inv};
    float4 o1 = {acc[4] * inv, acc[5] * inv, acc[6] * inv, acc[7] * inv};
    float* dst = O + ((size_t)bh * S2 + r0 + row) * DHEAD + cg * 8;
    *(float4*)dst       = o0;
    *(float4*)(dst + 4) = o1;
}

// ---------------------------------------------------------------------------
// Output projection: out[2048,1024] = gather(O)[2048,1024] @ w_out^T + b_out.
// A row r=(b,n): feature k = head*64+off gathered from O[b,head,seq_off+n,off].
// ---------------------------------------------------------------------------
__global__ __launch_bounds__(256) void proj_gemm(
    const float* __restrict__ Od,
    const float* __restrict__ W,    // w_out f32 [1024,1024]
    const float* __restrict__ Bo,   // b_out f32 [1024]
    float* __restrict__ out,        // f32 [2048,1024]
    int seq_off)
{
    __shared__ float As[16][68];
    __shared__ float Bs[16][68];
    const int t    = threadIdx.x;
    const int row0 = blockIdx.y * 64;
    const int col0 = blockIdx.x * 64;
    const int tx   = t & 15, ty = t >> 4;
    const int lrow = t >> 2;
    const int lk4  = (t & 3) * 4;
    float acc[4][4] = {};

    for (int k0 = 0; k0 < HDIM; k0 += 16) {
        int r = row0 + lrow;
        int bb = r >> 10, n = r & 1023;
        int k = k0 + lk4;
        int head = k >> 6, off = k & 63;
        float4 a = *(const float4*)(Od + ((size_t)(bb * NHEADS + head) * S2 + seq_off + n) * DHEAD + off);
        float4 ub = *(const float4*)(W + (size_t)(col0 + lrow) * HDIM + k0 + lk4);
        As[lk4 + 0][lrow] = a.x;
        As[lk4 + 1][lrow] = a.y;
        As[lk4 + 2][lrow] = a.z;
        As[lk4 + 3][lrow] = a.w;
        Bs[lk4 + 0][lrow] = ub.x;
        Bs[lk4 + 1][lrow] = ub.y;
        Bs[lk4 + 2][lrow] = ub.z;
        Bs[lk4 + 3][lrow] = ub.w;
        __syncthreads();
        #pragma unroll
        for (int kk = 0; kk < 16; ++kk) {
            float4 a4 = *(const float4*)&As[kk][ty * 4];
            float4 b4 = *(const float4*)&Bs[kk][tx * 4];
            float av[4] = {a4.x, a4.y, a4.z, a4.w};
            float bv[4] = {b4.x, b4.y, b4.z, b4.w};
            #pragma unroll
            for (int i = 0; i < 4; ++i)
                #pragma unroll
                for (int j = 0; j < 4; ++j)
                    acc[i][j] += av[i] * bv[j];
        }
        __syncthreads();
    }

    #pragma unroll
    for (int i = 0; i < 4; ++i) {
        int r = row0 + ty * 4 + i;
        float* dst = out + (size_t)r * HDIM + col0 + tx * 4;
        float4 o;
        o.x = acc[i][0] + Bo[col0 + tx * 4 + 0];
        o.y = acc[i][1] + Bo[col0 + tx * 4 + 1];
        o.z = acc[i][2] + Bo[col0 + tx * 4 + 2];
        o.w = acc[i][3] + Bo[col0 + tx * 4 + 3];
        *(float4*)dst = o;
    }
}

extern "C" void kernel_launch(void* const* d_in, const int* in_sizes, int n_in,
                              void* d_out, int out_size, void* d_ws, size_t ws_size,
                              hipStream_t stream) {
    const float* x    = (const float*)d_in[0];  // f32 [2,1024,1024]
    const float* x2   = (const float*)d_in[1];  // f32 [2,1024,1024]
    const float* wqkv = (const float*)d_in[2];  // f32 [3072,1024]
    const float* wout = (const float*)d_in[3];  // f32 [1024,1024]
    const float* bout = (const float*)d_in[4];  // f32 [1024]
    float* out = (float*)d_out;                 // f32, 2 x [2,1024,1024] concat

    // Workspace (f32): Q,K,V,O each [B=2, NH=16, S=2048, d=64] = 4,194,304 floats
    float* Q = (float*)d_ws;
    float* K = Q + 4194304;
    float* V = K + 4194304;
    float* O = V + 4194304;

    dim3 blk(256);
    dim3 g1(48, 32);   // 3072/64 cols x 2048/64 rows
    qkv_gemm<<<g1, blk, 0, stream>>>(x,  wqkv, Q, K, V, 0);
    qkv_gemm<<<g1, blk, 0, stream>>>(x2, wqkv, Q, K, V, NSEQ);

    dim3 ga(S2 / 32, NHEADS, NB);
    attn_kernel<<<ga, blk, 0, stream>>>(Q, K, V, O);

    dim3 g2(16, 32);   // 1024/64 cols x 2048/64 rows
    proj_gemm<<<g2, blk, 0, stream>>>(O, wout, bout, out,                     0);
    proj_gemm<<<g2, blk, 0, stream>>>(O, wout, bout, out + NB * NSEQ * HDIM,  NSEQ);
}

// Round 3
// 272.369 us; speedup vs baseline: 5.2434x; 5.2434x over previous
//
#include <hip/hip_runtime.h>

// B=2, N=1024/branch, H=1024, NH=16, d=64, S=2N=2048. I/O f32; compute bf16 MFMA.
#define NB      2
#define NSEQ    1024
#define S2      2048
#define HDIM    1024
#define NHEADS  16
#define DHEAD   64
#define ATT_SCALE 0.125f

typedef unsigned short ushort_t;
typedef __attribute__((ext_vector_type(8))) short short8;   // 8 bf16 = 4 VGPR (MFMA A/B frag)
typedef __attribute__((ext_vector_type(4))) float f32x4;    // MFMA C/D frag

__device__ __forceinline__ ushort_t f2bf(float f) {
    union { float f; unsigned int u; } c; c.f = f;
    unsigned int u = c.u;
    u += 0x7FFFu + ((u >> 16) & 1u);   // RTNE
    return (ushort_t)(u >> 16);
}

// ---------------------------------------------------------------------------
// One-shot f32 -> bf16 convert of x, x2, w_qkv, w_out into workspace.
// Grid = 8192 blocks x 256 thr, 4 float4 elems each; job by block range.
// ---------------------------------------------------------------------------
__global__ __launch_bounds__(256) void cvt_all(
    const float* __restrict__ x, const float* __restrict__ x2,
    const float* __restrict__ wqkv, const float* __restrict__ wout,
    ushort_t* __restrict__ Xb, ushort_t* __restrict__ Wqb, ushort_t* __restrict__ Wob)
{
    int b = blockIdx.x;
    const float* s; ushort_t* d; int i;
    if (b < 2048)      { s = x;    d = Xb;            i = b * 256 + threadIdx.x; }
    else if (b < 4096) { s = x2;   d = Xb + 2097152;  i = (b - 2048) * 256 + threadIdx.x; }
    else if (b < 7168) { s = wqkv; d = Wqb;           i = (b - 4096) * 256 + threadIdx.x; }
    else               { s = wout; d = Wob;           i = (b - 7168) * 256 + threadIdx.x; }
    float4 v = ((const float4*)s)[i];
    ushort4 o; o.x = f2bf(v.x); o.y = f2bf(v.y); o.z = f2bf(v.z); o.w = f2bf(v.w);
    ((ushort4*)d)[i] = o;
}

// ---------------------------------------------------------------------------
// QKV MFMA GEMM: C[4096,3072] = Xb @ Wqb^T. M-rows = [x rows | x2 rows].
// 128x128 tile, BK=32, 256 thr = 4 waves (2x2 of 64x64), 16x16x32 bf16 MFMA.
// Epilogue: Q,K -> [b,h,s,d] bf16; V -> transposed [b,h,d,s] bf16.
// ---------------------------------------------------------------------------
__global__ __launch_bounds__(256) void qkv_gemm_mfma(
    const ushort_t* __restrict__ Xb, const ushort_t* __restrict__ Wqb,
    ushort_t* __restrict__ Qb, ushort_t* __restrict__ Kb, ushort_t* __restrict__ Vtb)
{
    __shared__ ushort_t As[128][40];   // pitch 40 elem = 80 B: 16B-aligned rows, 2-way banks
    __shared__ ushort_t Bs[128][40];
    const int t = threadIdx.x;
    const int lane = t & 63, quad = lane >> 4, l15 = lane & 15;
    const int w = t >> 6;
    const int wm = (w >> 1) * 64, wn = (w & 1) * 64;
    const int r0 = blockIdx.y * 128, c0 = blockIdx.x * 128;

    f32x4 acc[4][4];
    #pragma unroll
    for (int i = 0; i < 4; ++i)
        #pragma unroll
        for (int j = 0; j < 4; ++j) acc[i][j] = (f32x4){0.f, 0.f, 0.f, 0.f};

    const int srow = t >> 2, sc8 = (t & 3) * 8;
    for (int k0 = 0; k0 < HDIM; k0 += 32) {
        __syncthreads();
        #pragma unroll
        for (int p = 0; p < 2; ++p) {
            int row = srow + p * 64;
            short8 va = *(const short8*)(Xb  + (size_t)(r0 + row) * HDIM + k0 + sc8);
            short8 vb = *(const short8*)(Wqb + (size_t)(c0 + row) * HDIM + k0 + sc8);
            *(short8*)&As[row][sc8] = va;
            *(short8*)&Bs[row][sc8] = vb;
        }
        __syncthreads();
        short8 af[4], bf[4];
        #pragma unroll
        for (int mi = 0; mi < 4; ++mi) af[mi] = *(const short8*)&As[wm + mi * 16 + l15][quad * 8];
        #pragma unroll
        for (int ni = 0; ni < 4; ++ni) bf[ni] = *(const short8*)&Bs[wn + ni * 16 + l15][quad * 8];
        #pragma unroll
        for (int mi = 0; mi < 4; ++mi)
            #pragma unroll
            for (int ni = 0; ni < 4; ++ni)
                acc[mi][ni] = __builtin_amdgcn_mfma_f32_16x16x32_bf16(af[mi], bf[ni], acc[mi][ni], 0, 0, 0);
    }

    const int branch = r0 >> 11;            // uniform per block
    const int bb     = (r0 & 2047) >> 10;
    const int qi     = c0 >> 10;            // 0=Q 1=K 2=V, uniform per block
    #pragma unroll
    for (int mi = 0; mi < 4; ++mi) {
        int sbase = branch * NSEQ + (r0 & 1023) + wm + mi * 16 + quad * 4;  // s for reg 0
        #pragma unroll
        for (int ni = 0; ni < 4; ++ni) {
            int cc = (c0 & 1023) + wn + ni * 16;
            int h  = cc >> 6;
            int dd = (cc & 63) + l15;
            if (qi == 2) {
                ushort4 pv;
                pv.x = f2bf(acc[mi][ni][0]); pv.y = f2bf(acc[mi][ni][1]);
                pv.z = f2bf(acc[mi][ni][2]); pv.w = f2bf(acc[mi][ni][3]);
                *(ushort4*)(Vtb + ((size_t)(bb * NHEADS + h) * DHEAD + dd) * S2 + sbase) = pv;
            } else {
                ushort_t* dst = (qi ? Kb : Qb) + ((size_t)(bb * NHEADS + h) * S2 + sbase) * DHEAD + dd;
                dst[0]   = f2bf(acc[mi][ni][0]);
                dst[64]  = f2bf(acc[mi][ni][1]);
                dst[128] = f2bf(acc[mi][ni][2]);
                dst[192] = f2bf(acc[mi][ni][3]);
            }
        }
    }
}

// ---------------------------------------------------------------------------
// MFMA flash attention per (b,h): Q[2048,64], K[2048,64], Vt[64,2048] bf16.
// Block = 64 q-rows, 4 waves (16 rows each); K-tiles of 64 keys, 32 iters.
// S in C-layout regs -> quad-shfl online softmax -> P via per-wave LDS rows
// (writer wave == reader wave: no barrier) -> PV MFMA. O bf16 [b,h,s,d].
// ---------------------------------------------------------------------------
__global__ __launch_bounds__(256) void attn_mfma(
    const ushort_t* __restrict__ Qb, const ushort_t* __restrict__ Kb,
    const ushort_t* __restrict__ Vtb, ushort_t* __restrict__ Ob)
{
    __shared__ ushort_t Qs[64][72];   // pitch 72 elem = 144 B: 16B-aligned, <=2-way banks on b128
    __shared__ ushort_t Ks[64][72];
    __shared__ ushort_t Vts[64][72];
    __shared__ ushort_t Ps[64][72];

    const int t = threadIdx.x, lane = t & 63, quad = lane >> 4, l15 = lane & 15, w = t >> 6;
    const int bh = blockIdx.z * NHEADS + blockIdx.y;
    const int r0 = blockIdx.x * 64;
    const ushort_t* Qh  = Qb  + (size_t)bh * S2 * DHEAD;
    const ushort_t* Kh  = Kb  + (size_t)bh * S2 * DHEAD;
    const ushort_t* Vth = Vtb + (size_t)bh * DHEAD * S2;

    #pragma unroll
    for (int p = 0; p < 2; ++p) {
        int idx = t + 256 * p, row = idx >> 3, c8 = (idx & 7) * 8;
        *(short8*)&Qs[row][c8] = *(const short8*)(Qh + (size_t)(r0 + row) * DHEAD + c8);
    }
    __syncthreads();
    short8 aq0 = *(const short8*)&Qs[16 * w + l15][quad * 8];
    short8 aq1 = *(const short8*)&Qs[16 * w + l15][32 + quad * 8];

    float mrow[4] = {-1e30f, -1e30f, -1e30f, -1e30f};
    float lrow[4] = {0.f, 0.f, 0.f, 0.f};
    f32x4 oacc[4];
    #pragma unroll
    for (int nt = 0; nt < 4; ++nt) oacc[nt] = (f32x4){0.f, 0.f, 0.f, 0.f};

    for (int kt = 0; kt < S2 / 64; ++kt) {
        __syncthreads();
        #pragma unroll
        for (int p = 0; p < 2; ++p) {
            int idx = t + 256 * p, row = idx >> 3, c8 = (idx & 7) * 8;
            *(short8*)&Ks[row][c8]  = *(const short8*)(Kh  + (size_t)(kt * 64 + row) * DHEAD + c8);
            *(short8*)&Vts[row][c8] = *(const short8*)(Vth + (size_t)row * S2 + kt * 64 + c8);
        }
        __syncthreads();

        f32x4 sacc[4];
        #pragma unroll
        for (int nt = 0; nt < 4; ++nt) sacc[nt] = (f32x4){0.f, 0.f, 0.f, 0.f};
        #pragma unroll
        for (int nt = 0; nt < 4; ++nt) {
            short8 bk0 = *(const short8*)&Ks[nt * 16 + l15][quad * 8];
            short8 bk1 = *(const short8*)&Ks[nt * 16 + l15][32 + quad * 8];
            sacc[nt] = __builtin_amdgcn_mfma_f32_16x16x32_bf16(aq0, bk0, sacc[nt], 0, 0, 0);
            sacc[nt] = __builtin_amdgcn_mfma_f32_16x16x32_bf16(aq1, bk1, sacc[nt], 0, 0, 0);
        }

        #pragma unroll
        for (int reg = 0; reg < 4; ++reg) {
            float s0 = sacc[0][reg] * ATT_SCALE;
            float s1 = sacc[1][reg] * ATT_SCALE;
            float s2 = sacc[2][reg] * ATT_SCALE;
            float s3 = sacc[3][reg] * ATT_SCALE;
            float mt = fmaxf(fmaxf(s0, s1), fmaxf(s2, s3));
            mt = fmaxf(mt, __shfl_xor(mt, 1));
            mt = fmaxf(mt, __shfl_xor(mt, 2));
            mt = fmaxf(mt, __shfl_xor(mt, 4));
            mt = fmaxf(mt, __shfl_xor(mt, 8));
            float mnew  = fmaxf(mrow[reg], mt);
            float alpha = __expf(mrow[reg] - mnew);
            float p0 = __expf(s0 - mnew);
            float p1 = __expf(s1 - mnew);
            float p2 = __expf(s2 - mnew);
            float p3 = __expf(s3 - mnew);
            int prow = 16 * w + quad * 4 + reg;
            Ps[prow][l15]      = f2bf(p0);
            Ps[prow][16 + l15] = f2bf(p1);
            Ps[prow][32 + l15] = f2bf(p2);
            Ps[prow][48 + l15] = f2bf(p3);
            float ls = p0 + p1 + p2 + p3;
            ls += __shfl_xor(ls, 1);
            ls += __shfl_xor(ls, 2);
            ls += __shfl_xor(ls, 4);
            ls += __shfl_xor(ls, 8);
            lrow[reg] = lrow[reg] * alpha + ls;
            mrow[reg] = mnew;
            oacc[0][reg] *= alpha; oacc[1][reg] *= alpha;
            oacc[2][reg] *= alpha; oacc[3][reg] *= alpha;
        }

        // PV: A = P (own wave's rows; same-wave LDS order, no barrier), B = Vt rows.
        #pragma unroll
        for (int kk = 0; kk < 2; ++kk) {
            short8 pa = *(const short8*)&Ps[16 * w + l15][kk * 32 + quad * 8];
            #pragma unroll
            for (int nt = 0; nt < 4; ++nt) {
                short8 bv = *(const short8*)&Vts[nt * 16 + l15][kk * 32 + quad * 8];
                oacc[nt] = __builtin_amdgcn_mfma_f32_16x16x32_bf16(pa, bv, oacc[nt], 0, 0, 0);
            }
        }
    }

    #pragma unroll
    for (int reg = 0; reg < 4; ++reg) {
        float inv = 1.f / lrow[reg];
        size_t rowoff = ((size_t)bh * S2 + r0 + 16 * w + quad * 4 + reg) * DHEAD;
        #pragma unroll
        for (int nt = 0; nt < 4; ++nt)
            Ob[rowoff + nt * 16 + l15] = f2bf(oacc[nt][reg] * inv);
    }
}

// ---------------------------------------------------------------------------
// Proj MFMA GEMM: out[4096,1024] (f32) = gather(O)[4096,1024] @ Wob^T + b_out.
// Row r: branch=r>>11, b, n; reads O[b, h=k>>6, branch*1024+n, k&63].
// ---------------------------------------------------------------------------
__global__ __launch_bounds__(256) void proj_gemm_mfma(
    const ushort_t* __restrict__ Ob, const ushort_t* __restrict__ Wob,
    const float* __restrict__ Bo, float* __restrict__ Out)
{
    __shared__ ushort_t As[128][40];
    __shared__ ushort_t Bs[128][40];
    const int t = threadIdx.x;
    const int lane = t & 63, quad = lane >> 4, l15 = lane & 15;
    const int w = t >> 6;
    const int wm = (w >> 1) * 64, wn = (w & 1) * 64;
    const int r0 = blockIdx.y * 128, c0 = blockIdx.x * 128;
    const int branch = r0 >> 11, bb = (r0 & 2047) >> 10;

    f32x4 acc[4][4];
    #pragma unroll
    for (int i = 0; i < 4; ++i)
        #pragma unroll
        for (int j = 0; j < 4; ++j) acc[i][j] = (f32x4){0.f, 0.f, 0.f, 0.f};

    const int srow = t >> 2, sc8 = (t & 3) * 8;
    for (int k0 = 0; k0 < HDIM; k0 += 32) {
        __syncthreads();
        #pragma unroll
        for (int p = 0; p < 2; ++p) {
            int row = srow + p * 64;
            int k = k0 + sc8;
            int h = k >> 6, ddb = k & 63;
            int s = branch * NSEQ + (r0 & 1023) + row;
            short8 va = *(const short8*)(Ob + ((size_t)(bb * NHEADS + h) * S2 + s) * DHEAD + ddb);
            short8 vb = *(const short8*)(Wob + (size_t)(c0 + row) * HDIM + k0 + sc8);
            *(short8*)&As[row][sc8] = va;
            *(short8*)&Bs[row][sc8] = vb;
        }
        __syncthreads();
        short8 af[4], bf[4];
        #pragma unroll
        for (int mi = 0; mi < 4; ++mi) af[mi] = *(const short8*)&As[wm + mi * 16 + l15][quad * 8];
        #pragma unroll
        for (int ni = 0; ni < 4; ++ni) bf[ni] = *(const short8*)&Bs[wn + ni * 16 + l15][quad * 8];
        #pragma unroll
        for (int mi = 0; mi < 4; ++mi)
            #pragma unroll
            for (int ni = 0; ni < 4; ++ni)
                acc[mi][ni] = __builtin_amdgcn_mfma_f32_16x16x32_bf16(af[mi], bf[ni], acc[mi][ni], 0, 0, 0);
    }

    #pragma unroll
    for (int mi = 0; mi < 4; ++mi) {
        int rb = r0 + wm + mi * 16 + quad * 4;
        #pragma unroll
        for (int ni = 0; ni < 4; ++ni) {
            int c = c0 + wn + ni * 16 + l15;
            float bias = Bo[c];
            Out[(size_t)(rb + 0) * HDIM + c] = acc[mi][ni][0] + bias;
            Out[(size_t)(rb + 1) * HDIM + c] = acc[mi][ni][1] + bias;
            Out[(size_t)(rb + 2) * HDIM + c] = acc[mi][ni][2] + bias;
            Out[(size_t)(rb + 3) * HDIM + c] = acc[mi][ni][3] + bias;
        }
    }
}

extern "C" void kernel_launch(void* const* d_in, const int* in_sizes, int n_in,
                              void* d_out, int out_size, void* d_ws, size_t ws_size,
                              hipStream_t stream) {
    const float* x    = (const float*)d_in[0];
    const float* x2   = (const float*)d_in[1];
    const float* wqkv = (const float*)d_in[2];
    const float* wout = (const float*)d_in[3];
    const float* bout = (const float*)d_in[4];
    float* out = (float*)d_out;

    // ws layout (bytes): Xb 8M | Wqb 6M | Wob 2M | Qb 8M | Kb 8M | Vtb 8M | Ob 8M = 48 MB
    char* ws = (char*)d_ws;
    ushort_t* Xb  = (ushort_t*)(ws);
    ushort_t* Wqb = (ushort_t*)(ws + (8u  << 20));
    ushort_t* Wob = (ushort_t*)(ws + (14u << 20));
    ushort_t* Qb  = (ushort_t*)(ws + (16u << 20));
    ushort_t* Kb  = (ushort_t*)(ws + (24u << 20));
    ushort_t* Vtb = (ushort_t*)(ws + (32u << 20));
    ushort_t* Ob  = (ushort_t*)(ws + (40u << 20));

    cvt_all<<<8192, 256, 0, stream>>>(x, x2, wqkv, wout, Xb, Wqb, Wob);
    qkv_gemm_mfma<<<dim3(24, 32), 256, 0, stream>>>(Xb, Wqb, Qb, Kb, Vtb);
    attn_mfma<<<dim3(S2 / 64, NHEADS, NB), 256, 0, stream>>>(Qb, Kb, Vtb, Ob);
    proj_gemm_mfma<<<dim3(8, 32), 256, 0, stream>>>(Ob, Wob, bout, out);
}